// Round 1
// baseline (1095.082 us; speedup 1.0000x reference)
//
#include <hip/hip_runtime.h>
#include <cstdint>

// Problem constants (B, BS, M, D) = (64, 8, 512, 256), neg = B/BS = 8
#define NEG_FILL_F (-10000000000.0f)
constexpr int BB     = 64;
constexpr int BS_    = 8;
constexpr int MM     = 512;
constexpr int DD     = 256;
constexpr int ROWS_X = BB * MM;           // 32768
constexpr int ROWS_Y = BS_ * MM;          // 4096
constexpr int ROWS_ALL = ROWS_X + ROWS_Y; // 36864

// ---------------------------------------------------------------------------
// Projections: C[r, j] = sum_d A[r, d] * W[j, d]   (A = x rows then y rows)
// Tile: 64x64 output, BK=16, 256 threads, 4x4 micro-tile per thread.
// grid = (ROWS_ALL/64, DD/64, 3)   z: 0=Wq, 1=Wk, 2=Wv
// ---------------------------------------------------------------------------
__global__ __launch_bounds__(256) void proj_kernel(
    const float* __restrict__ x, const float* __restrict__ y,
    const float* __restrict__ Wq, const float* __restrict__ Wk,
    const float* __restrict__ Wv,
    float* __restrict__ Q, float* __restrict__ K, float* __restrict__ V)
{
    const int z = blockIdx.z;
    const float* W = (z == 0) ? Wq : (z == 1 ? Wk : Wv);
    float* O       = (z == 0) ? Q  : (z == 1 ? K  : V);

    const int row0 = blockIdx.x * 64;
    const int col0 = blockIdx.y * 64;
    const float* A  = (row0 < ROWS_X) ? (x + (size_t)row0 * DD)
                                      : (y + (size_t)(row0 - ROWS_X) * DD);
    const float* Bm = W + (size_t)col0 * DD;

    __shared__ float As[64][17];
    __shared__ float Bs[64][17];

    const int t  = threadIdx.x;
    const int lr = t >> 2;          // 0..63  load row
    const int lc = (t & 3) * 4;     // 0,4,8,12 load col (float4)
    const int tx = t & 15, ty = t >> 4;

    float acc[4][4] = {};

    for (int k0 = 0; k0 < DD; k0 += 16) {
        float4 a4 = *(const float4*)(A  + (size_t)lr * DD + k0 + lc);
        float4 b4 = *(const float4*)(Bm + (size_t)lr * DD + k0 + lc);
        As[lr][lc+0] = a4.x; As[lr][lc+1] = a4.y; As[lr][lc+2] = a4.z; As[lr][lc+3] = a4.w;
        Bs[lr][lc+0] = b4.x; Bs[lr][lc+1] = b4.y; Bs[lr][lc+2] = b4.z; Bs[lr][lc+3] = b4.w;
        __syncthreads();
        #pragma unroll
        for (int k = 0; k < 16; ++k) {
            float ar[4], br[4];
            #pragma unroll
            for (int i = 0; i < 4; ++i) ar[i] = As[ty*4+i][k];
            #pragma unroll
            for (int j = 0; j < 4; ++j) br[j] = Bs[tx*4+j][k];
            #pragma unroll
            for (int i = 0; i < 4; ++i)
                #pragma unroll
                for (int j = 0; j < 4; ++j)
                    acc[i][j] += ar[i] * br[j];
        }
        __syncthreads();
    }
    #pragma unroll
    for (int i = 0; i < 4; ++i)
        #pragma unroll
        for (int j = 0; j < 4; ++j)
            O[(size_t)(row0 + ty*4 + i) * DD + col0 + tx*4 + j] = acc[i][j];
}

// ---------------------------------------------------------------------------
// Scores: S[i,j] = (mq[i] && mk[j]) ? Q_b[i,:]·K_b[j,:] : NEG_FILL
// mode 0: x-self (z = b in [0,64));  mode 1: y-self (z in [0,8));
// mode 2: xy      (z = n*8+s; bq = s*8+n, bk = s; also writes mask float).
// grid = (8, 8, nbatch), 256 threads, same 64x64 tile core.
// ---------------------------------------------------------------------------
__global__ __launch_bounds__(256) void scores_kernel(
    const float* __restrict__ Qbase, const float* __restrict__ Kbase,
    const int* __restrict__ mq_base, const int* __restrict__ mk_base,
    float* __restrict__ Sbase, float* __restrict__ Mbase, int mode)
{
    const int z = blockIdx.z;
    int bq, bk;
    if (mode == 2) { const int n = z >> 3, s = z & 7; bq = s * 8 + n; bk = s; }
    else           { bq = z; bk = z; }

    const int row0 = blockIdx.x * 64;
    const int col0 = blockIdx.y * 64;

    const float* A  = Qbase + (size_t)bq * MM * DD + (size_t)row0 * DD;
    const float* Bm = Kbase + (size_t)bk * MM * DD + (size_t)col0 * DD;
    const int* mq = mq_base + bq * MM;
    const int* mk = mk_base + bk * MM;
    float* S  = Sbase + (size_t)z * MM * MM;
    float* Mo = (mode == 2) ? (Mbase + (size_t)z * MM * MM) : nullptr;

    __shared__ float As[64][17];
    __shared__ float Bs[64][17];

    const int t  = threadIdx.x;
    const int lr = t >> 2;
    const int lc = (t & 3) * 4;
    const int tx = t & 15, ty = t >> 4;

    float acc[4][4] = {};

    for (int k0 = 0; k0 < DD; k0 += 16) {
        float4 a4 = *(const float4*)(A  + (size_t)lr * DD + k0 + lc);
        float4 b4 = *(const float4*)(Bm + (size_t)lr * DD + k0 + lc);
        As[lr][lc+0] = a4.x; As[lr][lc+1] = a4.y; As[lr][lc+2] = a4.z; As[lr][lc+3] = a4.w;
        Bs[lr][lc+0] = b4.x; Bs[lr][lc+1] = b4.y; Bs[lr][lc+2] = b4.z; Bs[lr][lc+3] = b4.w;
        __syncthreads();
        #pragma unroll
        for (int k = 0; k < 16; ++k) {
            float ar[4], br[4];
            #pragma unroll
            for (int i = 0; i < 4; ++i) ar[i] = As[ty*4+i][k];
            #pragma unroll
            for (int j = 0; j < 4; ++j) br[j] = Bs[tx*4+j][k];
            #pragma unroll
            for (int i = 0; i < 4; ++i)
                #pragma unroll
                for (int j = 0; j < 4; ++j)
                    acc[i][j] += ar[i] * br[j];
        }
        __syncthreads();
    }

    int mrow[4], mcol[4];
    #pragma unroll
    for (int i = 0; i < 4; ++i) mrow[i] = mq[row0 + ty*4 + i];
    #pragma unroll
    for (int j = 0; j < 4; ++j) mcol[j] = mk[col0 + tx*4 + j];

    #pragma unroll
    for (int i = 0; i < 4; ++i) {
        const size_t roff = (size_t)(row0 + ty*4 + i) * MM + col0 + tx*4;
        #pragma unroll
        for (int j = 0; j < 4; ++j) {
            const bool valid = (mrow[i] != 0) && (mcol[j] != 0);
            S[roff + j] = valid ? acc[i][j] : NEG_FILL_F;
            if (Mo) Mo[roff + j] = valid ? 1.0f : 0.0f;
        }
    }
}

// ---------------------------------------------------------------------------
// Row stats: per row of 512, compute (max, 1/sum(exp(v-max))).
// One wave per row, 4 rows per 256-thread block. grid = nrows/4.
// Fully-masked rows (all NEG_FILL): max=NEG_FILL, sum=512 -> uniform softmax,
// matching jax.nn.softmax semantics exactly.
// ---------------------------------------------------------------------------
__global__ __launch_bounds__(256) void stats_kernel(
    const float* __restrict__ S, float2* __restrict__ st)
{
    const int wid  = threadIdx.x >> 6;
    const int lane = threadIdx.x & 63;
    const int row  = blockIdx.x * 4 + wid;
    const float* r = S + (size_t)row * MM;

    float4 v0 = *(const float4*)(r + lane * 8);
    float4 v1 = *(const float4*)(r + lane * 8 + 4);

    float m = fmaxf(fmaxf(fmaxf(v0.x, v0.y), fmaxf(v0.z, v0.w)),
                    fmaxf(fmaxf(v1.x, v1.y), fmaxf(v1.z, v1.w)));
    #pragma unroll
    for (int off = 32; off; off >>= 1) m = fmaxf(m, __shfl_xor(m, off));

    float s = __expf(v0.x - m) + __expf(v0.y - m) + __expf(v0.z - m) + __expf(v0.w - m)
            + __expf(v1.x - m) + __expf(v1.y - m) + __expf(v1.z - m) + __expf(v1.w - m);
    #pragma unroll
    for (int off = 32; off; off >>= 1) s += __shfl_xor(s, off);

    if (lane == 0) st[row] = make_float2(m, 1.0f / s);
}

// ---------------------------------------------------------------------------
// Context: O[i,n] = (1/sum_i) * sum_j exp(S[i,j]-max_i) * V[j,n]
// Tile 64(rows) x 128(cols), BK=32, 256 threads, 4x8 micro-tile.
// grid = (8, 2, nbatch)
// ---------------------------------------------------------------------------
__global__ __launch_bounds__(256) void ctx_kernel(
    const float* __restrict__ Sbase, const float2* __restrict__ stats,
    const float* __restrict__ Vbase, float* __restrict__ Obase)
{
    const int b = blockIdx.z;
    const float*  S  = Sbase + (size_t)b * MM * MM;
    const float*  Vb = Vbase + (size_t)b * MM * DD;
    const float2* st = stats + (size_t)b * MM;
    float*        O  = Obase + (size_t)b * MM * DD;

    const int row0 = blockIdx.x * 64;
    const int col0 = blockIdx.y * 128;

    __shared__ float Ps[64][36];    // stride 36 floats = 144B (16B aligned)
    __shared__ float Vs[32][132];   // stride 132 floats = 528B (16B aligned)

    const int t  = threadIdx.x;
    const int tx = t & 15, ty = t >> 4;
    const int pr = t >> 2, pc = (t & 3) * 8;     // P-tile load: 64x32, 8/thread
    const int vr = t >> 3, vc = (t & 7) * 16;    // V-tile load: 32x128, 16/thread

    float acc[4][8] = {};
    const float pm = st[row0 + pr].x;

    for (int j0 = 0; j0 < MM; j0 += 32) {
        float4 s0 = *(const float4*)(S + (size_t)(row0 + pr) * MM + j0 + pc);
        float4 s1 = *(const float4*)(S + (size_t)(row0 + pr) * MM + j0 + pc + 4);
        Ps[pr][pc+0] = __expf(s0.x - pm);
        Ps[pr][pc+1] = __expf(s0.y - pm);
        Ps[pr][pc+2] = __expf(s0.z - pm);
        Ps[pr][pc+3] = __expf(s0.w - pm);
        Ps[pr][pc+4] = __expf(s1.x - pm);
        Ps[pr][pc+5] = __expf(s1.y - pm);
        Ps[pr][pc+6] = __expf(s1.z - pm);
        Ps[pr][pc+7] = __expf(s1.w - pm);

        const float* vp = Vb + (size_t)(j0 + vr) * DD + col0 + vc;
        float4 w0 = *(const float4*)(vp + 0);
        float4 w1 = *(const float4*)(vp + 4);
        float4 w2 = *(const float4*)(vp + 8);
        float4 w3 = *(const float4*)(vp + 12);
        *(float4*)&Vs[vr][vc + 0]  = w0;
        *(float4*)&Vs[vr][vc + 4]  = w1;
        *(float4*)&Vs[vr][vc + 8]  = w2;
        *(float4*)&Vs[vr][vc + 12] = w3;
        __syncthreads();

        #pragma unroll
        for (int k = 0; k < 32; ++k) {
            float ar[4];
            #pragma unroll
            for (int i = 0; i < 4; ++i) ar[i] = Ps[ty*4+i][k];
            float4 bv0 = *(const float4*)&Vs[k][tx*8];
            float4 bv1 = *(const float4*)&Vs[k][tx*8 + 4];
            const float br[8] = {bv0.x, bv0.y, bv0.z, bv0.w, bv1.x, bv1.y, bv1.z, bv1.w};
            #pragma unroll
            for (int i = 0; i < 4; ++i)
                #pragma unroll
                for (int j = 0; j < 8; ++j)
                    acc[i][j] += ar[i] * br[j];
        }
        __syncthreads();
    }

    #pragma unroll
    for (int i = 0; i < 4; ++i) {
        const float inv = st[row0 + ty*4 + i].y;
        float* op = O + (size_t)(row0 + ty*4 + i) * DD + col0 + tx*8;
        float4 o0 = make_float4(acc[i][0]*inv, acc[i][1]*inv, acc[i][2]*inv, acc[i][3]*inv);
        float4 o1 = make_float4(acc[i][4]*inv, acc[i][5]*inv, acc[i][6]*inv, acc[i][7]*inv);
        *(float4*)(op + 0) = o0;
        *(float4*)(op + 4) = o1;
    }
}

// ---------------------------------------------------------------------------
// In-place softmax transform of the scores_xy slot -> probs_xy.
// One block per row, 128 threads x float4.
// ---------------------------------------------------------------------------
__global__ __launch_bounds__(128) void softmax_apply(
    float* __restrict__ S, const float2* __restrict__ stats)
{
    const int row = blockIdx.x;
    const float2 st = stats[row];
    float4* r = (float4*)(S + (size_t)row * MM) + threadIdx.x;
    float4 v = *r;
    v.x = __expf(v.x - st.x) * st.y;
    v.y = __expf(v.y - st.x) * st.y;
    v.z = __expf(v.z - st.x) * st.y;
    v.w = __expf(v.w - st.x) * st.y;
    *r = v;
}

// ---------------------------------------------------------------------------
// y_len[n, s] = sum_i mask_y[s, i]; 64 threads, t = n*8 + s.
// ---------------------------------------------------------------------------
__global__ void ylen_kernel(const int* __restrict__ mask_y, float* __restrict__ out)
{
    const int t = threadIdx.x;
    const int s = t & 7;
    int c = 0;
    for (int i = 0; i < MM; ++i) c += (mask_y[s * MM + i] != 0);
    out[t] = (float)c;
}

// ---------------------------------------------------------------------------
extern "C" void kernel_launch(void* const* d_in, const int* in_sizes, int n_in,
                              void* d_out, int out_size, void* d_ws, size_t ws_size,
                              hipStream_t stream)
{
    const float* x      = (const float*)d_in[0];
    const float* y      = (const float*)d_in[1];
    const int*   mask_x = (const int*)d_in[2];
    const int*   mask_y = (const int*)d_in[3];
    const float* Wq     = (const float*)d_in[4];
    const float* Wk     = (const float*)d_in[5];
    const float* Wv     = (const float*)d_in[6];
    float* out = (float*)d_out;

    // Workspace layout (floats): Q | K | V | stats  (~113.8 MB total)
    float* Q = (float*)d_ws;
    float* K = Q + (size_t)ROWS_ALL * DD;
    float* V = K + (size_t)ROWS_ALL * DD;
    float2* stats_x  = (float2*)(V + (size_t)ROWS_ALL * DD);
    float2* stats_y  = stats_x + ROWS_X;
    float2* stats_xy = stats_y + ROWS_Y;

    // Output slots (floats, concatenated in reference return order)
    float* out_ctx_x = out;                 // 64*512*256   = 8388608
    float* out_ctx_y = out + 8388608;       // 8*512*256    = 1048576
    float* out_sx    = out + 9437184;       // 64*512*512   = 16777216
    float* out_sy    = out + 26214400;      // 8*512*512    = 2097152
    float* out_pxy   = out + 28311552;      // 8*8*512*512  = 16777216
    float* out_mxy   = out + 45088768;      // 8*8*512*512  = 16777216
    float* out_ylen  = out + 61865984;      // 8*8          = 64

    const float* Qx = Q;  const float* Qy = Q + (size_t)ROWS_X * DD;
    const float* Kx = K;  const float* Ky = K + (size_t)ROWS_X * DD;
    const float* Vx = V;  const float* Vy = V + (size_t)ROWS_X * DD;

    // 1. Projections: Q/K/V for x-rows and y-rows
    proj_kernel<<<dim3(ROWS_ALL / 64, DD / 64, 3), 256, 0, stream>>>(
        x, y, Wq, Wk, Wv, Q, K, V);

    // 2. Masked scores (written straight into their output slots)
    scores_kernel<<<dim3(8, 8, 64), 256, 0, stream>>>(Qx, Kx, mask_x, mask_x, out_sx,  nullptr, 0);
    scores_kernel<<<dim3(8, 8, 8),  256, 0, stream>>>(Qy, Ky, mask_y, mask_y, out_sy,  nullptr, 1);
    scores_kernel<<<dim3(8, 8, 64), 256, 0, stream>>>(Qx, Ky, mask_x, mask_y, out_pxy, out_mxy, 2);

    // 3. Softmax row stats
    stats_kernel<<<ROWS_X / 4, 256, 0, stream>>>(out_sx,  stats_x);
    stats_kernel<<<ROWS_Y / 4, 256, 0, stream>>>(out_sy,  stats_y);
    stats_kernel<<<ROWS_X / 4, 256, 0, stream>>>(out_pxy, stats_xy);

    // 4. Context GEMMs (softmax applied on the fly)
    ctx_kernel<<<dim3(8, 2, 64), 256, 0, stream>>>(out_sx, stats_x, Vx, out_ctx_x);
    ctx_kernel<<<dim3(8, 2, 8),  256, 0, stream>>>(out_sy, stats_y, Vy, out_ctx_y);

    // 5. scores_xy -> probs_xy in place
    softmax_apply<<<ROWS_X, 128, 0, stream>>>(out_pxy, stats_xy);

    // 6. y_len
    ylen_kernel<<<1, 64, 0, stream>>>(mask_y, out_ylen);
}

// Round 3
// 880.032 us; speedup vs baseline: 1.2444x; 1.2444x over previous
//
#include <hip/hip_runtime.h>
#include <cstdint>

// Problem constants (B, BS, M, D) = (64, 8, 512, 256), neg = B/BS = 8
#define NEG_FILL_F (-10000000000.0f)
constexpr int BB     = 64;
constexpr int BS_    = 8;
constexpr int MM     = 512;
constexpr int DD     = 256;
constexpr int ROWS_X = BB * MM;           // 32768
constexpr int ROWS_Y = BS_ * MM;          // 4096
constexpr int ROWS_ALL = ROWS_X + ROWS_Y; // 36864

// ---------------------------------------------------------------------------
// Shared NT GEMM core: C[128,128] tile of A[128,K] · B[128,K]^T.
// LDS holds K-transposed tiles (As[k][row]) so fragments are ds_read_b128.
// 256 threads, 8x8 micro-tile: rows {ty*4+i, ty*4+64+i}, cols {tx*4+j, +64}.
// A_/B_ MUST be pre-offset to the tile origin (row0/col0).
// ---------------------------------------------------------------------------
#define GEMM_NT_CORE(A_, lda_, B_, ldb_, K_)                                   \
    for (int k0 = 0; k0 < (K_); k0 += 16) {                                    \
        _Pragma("unroll")                                                      \
        for (int l = 0; l < 2; ++l) {                                          \
            const int r  = (t >> 2) + l * 64;                                  \
            const int kk = (t & 3) * 4;                                        \
            float4 a = *(const float4*)((A_) + (size_t)r * (lda_) + k0 + kk);  \
            As[kk+0][r] = a.x; As[kk+1][r] = a.y;                              \
            As[kk+2][r] = a.z; As[kk+3][r] = a.w;                              \
            float4 b = *(const float4*)((B_) + (size_t)r * (ldb_) + k0 + kk);  \
            Bs[kk+0][r] = b.x; Bs[kk+1][r] = b.y;                              \
            Bs[kk+2][r] = b.z; Bs[kk+3][r] = b.w;                              \
        }                                                                      \
        __syncthreads();                                                       \
        _Pragma("unroll")                                                      \
        for (int k = 0; k < 16; ++k) {                                         \
            float4 a0 = *(const float4*)&As[k][ty * 4];                        \
            float4 a1 = *(const float4*)&As[k][ty * 4 + 64];                   \
            float4 b0 = *(const float4*)&Bs[k][tx * 4];                        \
            float4 b1 = *(const float4*)&Bs[k][tx * 4 + 64];                   \
            float ar[8] = {a0.x,a0.y,a0.z,a0.w,a1.x,a1.y,a1.z,a1.w};           \
            float br[8] = {b0.x,b0.y,b0.z,b0.w,b1.x,b1.y,b1.z,b1.w};           \
            _Pragma("unroll")                                                  \
            for (int i = 0; i < 8; ++i)                                        \
                _Pragma("unroll")                                              \
                for (int j = 0; j < 8; ++j)                                    \
                    acc[i][j] += ar[i] * br[j];                                \
        }                                                                      \
        __syncthreads();                                                       \
    }

// ---------------------------------------------------------------------------
// Projections: O[r, j] = sum_d A[r, d] * W[j, d]
// grid = (ROWS_ALL/128, DD/128, 3)   z: 0=Wq, 1=Wk, 2=Wv
// ---------------------------------------------------------------------------
__global__ __launch_bounds__(256) void proj_kernel(
    const float* __restrict__ x, const float* __restrict__ y,
    const float* __restrict__ Wq, const float* __restrict__ Wk,
    const float* __restrict__ Wv,
    float* __restrict__ Q, float* __restrict__ K, float* __restrict__ V)
{
    const int z = blockIdx.z;
    const float* W = (z == 0) ? Wq : (z == 1 ? Wk : Wv);
    float* O       = (z == 0) ? Q  : (z == 1 ? K  : V);

    const int row0 = blockIdx.x * 128;
    const int col0 = blockIdx.y * 128;
    const float* A  = (row0 < ROWS_X) ? (x + (size_t)row0 * DD)
                                      : (y + (size_t)(row0 - ROWS_X) * DD);
    const float* Bm = W + (size_t)col0 * DD;

    __shared__ float As[16][132];
    __shared__ float Bs[16][132];

    const int t  = threadIdx.x;
    const int tx = t & 15, ty = t >> 4;
    float acc[8][8] = {};

    GEMM_NT_CORE(A, DD, Bm, DD, DD)

    #pragma unroll
    for (int i = 0; i < 8; ++i) {
        const int r = row0 + ty * 4 + (i & 3) + (i >> 2) * 64;
        float* op = O + (size_t)r * DD + col0 + tx * 4;
        *(float4*)op        = make_float4(acc[i][0], acc[i][1], acc[i][2], acc[i][3]);
        *(float4*)(op + 64) = make_float4(acc[i][4], acc[i][5], acc[i][6], acc[i][7]);
    }
}

// ---------------------------------------------------------------------------
// Scores: S[i,j] = (mq[i] && mk[j]) ? Q_b[i,:]·K_b[j,:] : NEG_FILL
// mode 0: x-self; mode 1: y-self; mode 2: xy (bq = s*8+n, bk = s, writes mask)
// grid = (4, 4, nbatch)
// ---------------------------------------------------------------------------
__global__ __launch_bounds__(256) void scores_kernel(
    const float* __restrict__ Qbase, const float* __restrict__ Kbase,
    const int* __restrict__ mq_base, const int* __restrict__ mk_base,
    float* __restrict__ Sbase, float* __restrict__ Mbase, int mode)
{
    const int z = blockIdx.z;
    int bq, bk;
    if (mode == 2) { const int n = z >> 3, s = z & 7; bq = s * 8 + n; bk = s; }
    else           { bq = z; bk = z; }

    const int row0 = blockIdx.x * 128;
    const int col0 = blockIdx.y * 128;

    const float* A  = Qbase + (size_t)bq * MM * DD + (size_t)row0 * DD;
    const float* Bm = Kbase + (size_t)bk * MM * DD + (size_t)col0 * DD;
    const int* mq = mq_base + bq * MM;
    const int* mk = mk_base + bk * MM;
    float* S  = Sbase + (size_t)z * MM * MM;
    float* Mo = (mode == 2) ? (Mbase + (size_t)z * MM * MM) : nullptr;

    __shared__ float As[16][132];
    __shared__ float Bs[16][132];

    const int t  = threadIdx.x;
    const int tx = t & 15, ty = t >> 4;
    float acc[8][8] = {};

    GEMM_NT_CORE(A, DD, Bm, DD, DD)

    int mrow[8], mcol[8];
    #pragma unroll
    for (int i = 0; i < 8; ++i) {
        mrow[i] = mq[row0 + ty * 4 + (i & 3) + (i >> 2) * 64];
        mcol[i] = mk[col0 + tx * 4 + (i & 3) + (i >> 2) * 64];
    }

    #pragma unroll
    for (int i = 0; i < 8; ++i) {
        const int r = row0 + ty * 4 + (i & 3) + (i >> 2) * 64;
        const size_t roff = (size_t)r * MM + col0 + tx * 4;
        float sv[8], mv[8];
        #pragma unroll
        for (int j = 0; j < 8; ++j) {
            const bool valid = (mrow[i] != 0) && (mcol[j] != 0);
            sv[j] = valid ? acc[i][j] : NEG_FILL_F;
            mv[j] = valid ? 1.0f : 0.0f;
        }
        *(float4*)(S + roff)      = make_float4(sv[0], sv[1], sv[2], sv[3]);
        *(float4*)(S + roff + 64) = make_float4(sv[4], sv[5], sv[6], sv[7]);
        if (Mo) {
            *(float4*)(Mo + roff)      = make_float4(mv[0], mv[1], mv[2], mv[3]);
            *(float4*)(Mo + roff + 64) = make_float4(mv[4], mv[5], mv[6], mv[7]);
        }
    }
}

// ---------------------------------------------------------------------------
// Row stats: per row of 512, (max, 1/sum(exp(v-max))). One wave per row.
// Fully-masked rows -> uniform softmax, matching jax semantics.
// ---------------------------------------------------------------------------
__global__ __launch_bounds__(256) void stats_kernel(
    const float* __restrict__ S, float2* __restrict__ st)
{
    const int wid  = threadIdx.x >> 6;
    const int lane = threadIdx.x & 63;
    const int row  = blockIdx.x * 4 + wid;
    const float* r = S + (size_t)row * MM;

    float4 v0 = *(const float4*)(r + lane * 8);
    float4 v1 = *(const float4*)(r + lane * 8 + 4);

    float m = fmaxf(fmaxf(fmaxf(v0.x, v0.y), fmaxf(v0.z, v0.w)),
                    fmaxf(fmaxf(v1.x, v1.y), fmaxf(v1.z, v1.w)));
    #pragma unroll
    for (int off = 32; off; off >>= 1) m = fmaxf(m, __shfl_xor(m, off));

    float s = __expf(v0.x - m) + __expf(v0.y - m) + __expf(v0.z - m) + __expf(v0.w - m)
            + __expf(v1.x - m) + __expf(v1.y - m) + __expf(v1.z - m) + __expf(v1.w - m);
    #pragma unroll
    for (int off = 32; off; off >>= 1) s += __shfl_xor(s, off);

    if (lane == 0) st[row] = make_float2(m, 1.0f / s);
}

// ---------------------------------------------------------------------------
// Context: O[i,n] = (1/sum_i) * sum_j exp(S[i,j]-max_i) * V[j,n]
// 128x128 tile, BK=16 over j. P staged K-transposed with exp fused on load;
// V staged naturally. grid = (4, 2, nbatch)
// BUGFIX R2->R3: S row read must be (row0 + r), not local r.
// ---------------------------------------------------------------------------
__global__ __launch_bounds__(256) void ctx_kernel(
    const float* __restrict__ Sbase, const float2* __restrict__ stats,
    const float* __restrict__ Vbase, float* __restrict__ Obase)
{
    const int b = blockIdx.z;
    const float*  S  = Sbase + (size_t)b * MM * MM;
    const float*  Vb = Vbase + (size_t)b * MM * DD;
    const float2* st = stats + (size_t)b * MM;
    float*        O  = Obase + (size_t)b * MM * DD;

    const int row0 = blockIdx.x * 128;
    const int col0 = blockIdx.y * 128;

    __shared__ float Ps[16][132];
    __shared__ float Vs[16][132];

    const int t  = threadIdx.x;
    const int tx = t & 15, ty = t >> 4;
    float acc[8][8] = {};

    // per-thread staging rows (fixed across k0 steps)
    const int pr0 = (t >> 2);
    const float pm0 = st[row0 + pr0].x;
    const float pm1 = st[row0 + pr0 + 64].x;

    for (int j0 = 0; j0 < MM; j0 += 16) {
        #pragma unroll
        for (int l = 0; l < 2; ++l) {
            const int r  = pr0 + l * 64;
            const int kk = (t & 3) * 4;
            const float pm = l ? pm1 : pm0;
            float4 s4 = *(const float4*)(S + (size_t)(row0 + r) * MM + j0 + kk);
            Ps[kk+0][r] = __expf(s4.x - pm);
            Ps[kk+1][r] = __expf(s4.y - pm);
            Ps[kk+2][r] = __expf(s4.z - pm);
            Ps[kk+3][r] = __expf(s4.w - pm);
            // V tile: 16 rows x 128 cols, coalesced float4
            const int vr = (t >> 5) + l * 8;
            const int vc = (t & 31) * 4;
            float4 v4 = *(const float4*)(Vb + (size_t)(j0 + vr) * DD + col0 + vc);
            *(float4*)&Vs[vr][vc] = v4;
        }
        __syncthreads();
        #pragma unroll
        for (int k = 0; k < 16; ++k) {
            float4 a0 = *(const float4*)&Ps[k][ty * 4];
            float4 a1 = *(const float4*)&Ps[k][ty * 4 + 64];
            float4 b0 = *(const float4*)&Vs[k][tx * 4];
            float4 b1 = *(const float4*)&Vs[k][tx * 4 + 64];
            float ar[8] = {a0.x,a0.y,a0.z,a0.w,a1.x,a1.y,a1.z,a1.w};
            float br[8] = {b0.x,b0.y,b0.z,b0.w,b1.x,b1.y,b1.z,b1.w};
            #pragma unroll
            for (int i = 0; i < 8; ++i)
                #pragma unroll
                for (int j = 0; j < 8; ++j)
                    acc[i][j] += ar[i] * br[j];
        }
        __syncthreads();
    }

    #pragma unroll
    for (int i = 0; i < 8; ++i) {
        const int r = row0 + ty * 4 + (i & 3) + (i >> 2) * 64;
        const float inv = st[r].y;
        float* op = O + (size_t)r * DD + col0 + tx * 4;
        *(float4*)op = make_float4(acc[i][0]*inv, acc[i][1]*inv, acc[i][2]*inv, acc[i][3]*inv);
        *(float4*)(op + 64) = make_float4(acc[i][4]*inv, acc[i][5]*inv, acc[i][6]*inv, acc[i][7]*inv);
    }
}

// ---------------------------------------------------------------------------
// In-place softmax transform of the scores_xy slot -> probs_xy.
// ---------------------------------------------------------------------------
__global__ __launch_bounds__(128) void softmax_apply(
    float* __restrict__ S, const float2* __restrict__ stats)
{
    const int row = blockIdx.x;
    const float2 st = stats[row];
    float4* r = (float4*)(S + (size_t)row * MM) + threadIdx.x;
    float4 v = *r;
    v.x = __expf(v.x - st.x) * st.y;
    v.y = __expf(v.y - st.x) * st.y;
    v.z = __expf(v.z - st.x) * st.y;
    v.w = __expf(v.w - st.x) * st.y;
    *r = v;
}

// ---------------------------------------------------------------------------
// y_len[n, s] = sum_i mask_y[s, i]
// ---------------------------------------------------------------------------
__global__ void ylen_kernel(const int* __restrict__ mask_y, float* __restrict__ out)
{
    const int t = threadIdx.x;
    const int s = t & 7;
    int c = 0;
    for (int i = 0; i < MM; ++i) c += (mask_y[s * MM + i] != 0);
    out[t] = (float)c;
}

// ---------------------------------------------------------------------------
extern "C" void kernel_launch(void* const* d_in, const int* in_sizes, int n_in,
                              void* d_out, int out_size, void* d_ws, size_t ws_size,
                              hipStream_t stream)
{
    const float* x      = (const float*)d_in[0];
    const float* y      = (const float*)d_in[1];
    const int*   mask_x = (const int*)d_in[2];
    const int*   mask_y = (const int*)d_in[3];
    const float* Wq     = (const float*)d_in[4];
    const float* Wk     = (const float*)d_in[5];
    const float* Wv     = (const float*)d_in[6];
    float* out = (float*)d_out;

    // Workspace layout (floats): Q | K | V | stats  (~113.8 MB total)
    float* Q = (float*)d_ws;
    float* K = Q + (size_t)ROWS_ALL * DD;
    float* V = K + (size_t)ROWS_ALL * DD;
    float2* stats_x  = (float2*)(V + (size_t)ROWS_ALL * DD);
    float2* stats_y  = stats_x + ROWS_X;
    float2* stats_xy = stats_y + ROWS_Y;

    // Output slots (floats, concatenated in reference return order)
    float* out_ctx_x = out;                 // 64*512*256   = 8388608
    float* out_ctx_y = out + 8388608;       // 8*512*256    = 1048576
    float* out_sx    = out + 9437184;       // 64*512*512   = 16777216
    float* out_sy    = out + 26214400;      // 8*512*512    = 2097152
    float* out_pxy   = out + 28311552;      // 8*8*512*512  = 16777216
    float* out_mxy   = out + 45088768;      // 8*8*512*512  = 16777216
    float* out_ylen  = out + 61865984;      // 8*8          = 64

    const float* Qx = Q;  const float* Qy = Q + (size_t)ROWS_X * DD;
    const float* Kx = K;  const float* Ky = K + (size_t)ROWS_X * DD;
    const float* Vx = V;  const float* Vy = V + (size_t)ROWS_X * DD;

    // 1. Projections
    proj_kernel<<<dim3(ROWS_ALL / 128, DD / 128, 3), 256, 0, stream>>>(
        x, y, Wq, Wk, Wv, Q, K, V);

    // 2. Masked scores straight into output slots
    scores_kernel<<<dim3(4, 4, 64), 256, 0, stream>>>(Qx, Kx, mask_x, mask_x, out_sx,  nullptr, 0);
    scores_kernel<<<dim3(4, 4, 8),  256, 0, stream>>>(Qy, Ky, mask_y, mask_y, out_sy,  nullptr, 1);
    scores_kernel<<<dim3(4, 4, 64), 256, 0, stream>>>(Qx, Ky, mask_x, mask_y, out_pxy, out_mxy, 2);

    // 3. Softmax row stats
    stats_kernel<<<ROWS_X / 4, 256, 0, stream>>>(out_sx,  stats_x);
    stats_kernel<<<ROWS_Y / 4, 256, 0, stream>>>(out_sy,  stats_y);
    stats_kernel<<<ROWS_X / 4, 256, 0, stream>>>(out_pxy, stats_xy);

    // 4. Context GEMMs (softmax fused)
    ctx_kernel<<<dim3(4, 2, 64), 256, 0, stream>>>(out_sx, stats_x, Vx, out_ctx_x);
    ctx_kernel<<<dim3(4, 2, 8),  256, 0, stream>>>(out_sy, stats_y, Vy, out_ctx_y);

    // 5. scores_xy -> probs_xy in place
    softmax_apply<<<ROWS_X, 128, 0, stream>>>(out_pxy, stats_xy);

    // 6. y_len
    ylen_kernel<<<1, 64, 0, stream>>>(mask_y, out_ylen);
}

// Round 5
// 568.661 us; speedup vs baseline: 1.9257x; 1.5476x over previous
//
#include <hip/hip_runtime.h>
#include <cstdint>

// Problem constants (B, BS, M, D) = (64, 8, 512, 256), neg = B/BS = 8
#define NEG_FILL_F (-10000000000.0f)
constexpr int BB     = 64;
constexpr int BS_    = 8;
constexpr int MM     = 512;
constexpr int DD     = 256;
constexpr int ROWS_X = BB * MM;           // 32768
constexpr int ROWS_Y = BS_ * MM;          // 4096
constexpr int ROWS_ALL = ROWS_X + ROWS_Y; // 36864
constexpr int K3     = 768;               // triple-split K' = 3*DD

typedef __attribute__((ext_vector_type(8))) short short8;   // 8 bf16 = 4 VGPRs
typedef __attribute__((ext_vector_type(4))) float f32x4;    // MFMA C/D

__device__ inline unsigned short rne_bf16(float f) {
    unsigned int u = __float_as_uint(f);
    u = (u + 0x7FFFu + ((u >> 16) & 1u)) >> 16;
    return (unsigned short)u;
}
__device__ inline float bf2f(unsigned short h) {
    return __uint_as_float(((unsigned int)h) << 16);
}

__device__ inline f32x4 mfma16(short8 a, short8 b, f32x4 c) {
    return __builtin_amdgcn_mfma_f32_16x16x32_bf16(a, b, c, 0, 0, 0);
}

// Fragment loads + 16 MFMAs for one kk step. LDS layout: T[row][k], row-major.
// A-layout: lane holds A[m=lid][k=quad*8+j]; B: B[k=quad*8+j][n=lid].
template<int LDW>
__device__ inline void mfma_tiles(const unsigned short (*Ab)[LDW],
                                  const unsigned short (*Bb)[LDW],
                                  int kk, int wrow, int wcol, int lid, int quad,
                                  f32x4 acc[4][4])
{
    short8 af[4], bfr[4];
    #pragma unroll
    for (int i = 0; i < 4; ++i)
        af[i] = *(const short8*)&Ab[wrow + i * 16 + lid][kk + quad * 8];
    #pragma unroll
    for (int j = 0; j < 4; ++j)
        bfr[j] = *(const short8*)&Bb[wcol + j * 16 + lid][kk + quad * 8];
    #pragma unroll
    for (int i = 0; i < 4; ++i)
        #pragma unroll
        for (int j = 0; j < 4; ++j)
            acc[i][j] = mfma16(af[i], bfr[j], acc[i][j]);
}

// Stage a 128-row x 96-bf16 tile from a pre-split (stride-768) bf16 array.
__device__ inline void stage_768(unsigned short (*dst)[104],
                                 const unsigned short* __restrict__ src,
                                 int ck, int t)
{
    #pragma unroll
    for (int s = 0; s < 6; ++s) {
        const int c   = s * 256 + t;        // 0..1535
        const int row = c / 12;
        const int kc  = (c % 12) * 8;
        short8 v = *(const short8*)(src + (size_t)row * K3 + ck * 96 + kc);
        *(short8*)&dst[row][kc] = v;
    }
}

// Stage a 128-row x 32-f32 tile as 96 bf16 triple-split A-form (h,l,h).
// BUGFIX R4->R5: must cover all 128x32 floats (s<4, 8 float4-chunks/row),
// R4's s<2 left LDS cols 48..95 uninitialized -> NaN.
__device__ inline void stage_x96(unsigned short (*dst)[104],
                                 const float* __restrict__ src,
                                 int ck, int t)
{
    #pragma unroll
    for (int s = 0; s < 4; ++s) {
        const int c   = s * 256 + t;        // 0..1023
        const int row = c >> 3;             // 0..127
        const int q4  = (c & 7) * 4;        // 0,4,...,28
        float4 v = *(const float4*)(src + (size_t)row * DD + ck * 32 + q4);
        const float fv[4] = {v.x, v.y, v.z, v.w};
        unsigned short o[12];
        #pragma unroll
        for (int e = 0; e < 4; ++e) {
            unsigned short h = rne_bf16(fv[e]);
            unsigned short l = rne_bf16(fv[e] - bf2f(h));
            o[e*3+0] = h; o[e*3+1] = l; o[e*3+2] = h;
        }
        ushort4* p = (ushort4*)&dst[row][q4 * 3];
        p[0] = make_ushort4(o[0], o[1], o[2],  o[3]);
        p[1] = make_ushort4(o[4], o[5], o[6],  o[7]);
        p[2] = make_ushort4(o[8], o[9], o[10], o[11]);
    }
}

// ---------------------------------------------------------------------------
// W -> Wb: [3][256][768] triple-split B-form (h,h,l). 96 blocks x 256.
// ---------------------------------------------------------------------------
__global__ __launch_bounds__(256) void convw_kernel(
    const float* __restrict__ Wq, const float* __restrict__ Wk,
    const float* __restrict__ Wv, unsigned short* __restrict__ Wb)
{
    const int g  = blockIdx.x * 256 + threadIdx.x;   // < 24576
    const int e  = g * 8;                            // over 3*65536
    const int zi = e >> 16;
    const int off = e & 65535;
    const float* W = (zi == 0) ? Wq : (zi == 1 ? Wk : Wv);
    float4 v0 = *(const float4*)(W + off);
    float4 v1 = *(const float4*)(W + off + 4);
    const float fv[8] = {v0.x, v0.y, v0.z, v0.w, v1.x, v1.y, v1.z, v1.w};
    unsigned short o[24];
    #pragma unroll
    for (int i = 0; i < 8; ++i) {
        unsigned short h = rne_bf16(fv[i]);
        unsigned short l = rne_bf16(fv[i] - bf2f(h));
        o[i*3+0] = h; o[i*3+1] = h; o[i*3+2] = l;
    }
    unsigned short* dst = Wb + (size_t)zi * 196608 + (size_t)off * 3;
    #pragma unroll
    for (int s = 0; s < 3; ++s) {
        short8 v;
        #pragma unroll
        for (int e2 = 0; e2 < 8; ++e2) v[e2] = (short)o[s*8+e2];
        *(short8*)(dst + s * 8) = v;
    }
}

// ---------------------------------------------------------------------------
// Projections via MFMA: O[r,n] = sum_d A[r,d] W[n,d] (triple-split, K'=768).
// Epilogue: z=0 -> Qa (A-form split), z=1 -> Kb (B-form split),
//           z=2 -> Vt[b][d][j] plain bf16 (transposed for ctx B-operand).
// grid = (288, 2, 3)
// ---------------------------------------------------------------------------
__global__ __launch_bounds__(256) void proj_kernel(
    const float* __restrict__ x, const float* __restrict__ y,
    const unsigned short* __restrict__ Wb,
    unsigned short* __restrict__ Qa, unsigned short* __restrict__ Kb,
    unsigned short* __restrict__ Vt)
{
    const int z    = blockIdx.z;
    const int row0 = blockIdx.x * 128;
    const int col0 = blockIdx.y * 128;
    const float* A = (row0 < ROWS_X) ? (x + (size_t)row0 * DD)
                                     : (y + (size_t)(row0 - ROWS_X) * DD);
    const unsigned short* Bsrc = Wb + (size_t)z * 196608 + (size_t)col0 * K3;

    __shared__ unsigned short Ab[128][104];
    __shared__ unsigned short Bb[128][104];

    const int t = threadIdx.x;
    const int wave = t >> 6, lane = t & 63, quad = lane >> 4, lid = lane & 15;
    const int wrow = (wave & 1) * 64, wcol = (wave >> 1) * 64;

    f32x4 acc[4][4];
    #pragma unroll
    for (int i = 0; i < 4; ++i)
        #pragma unroll
        for (int j = 0; j < 4; ++j) acc[i][j] = (f32x4){0.f, 0.f, 0.f, 0.f};

    for (int ck = 0; ck < 8; ++ck) {
        stage_x96(Ab, A, ck, t);
        stage_768(Bb, Bsrc, ck, t);
        __syncthreads();
        #pragma unroll
        for (int kk = 0; kk < 96; kk += 32)
            mfma_tiles<104>(Ab, Bb, kk, wrow, wcol, lid, quad, acc);
        __syncthreads();
    }

    if (z == 2) {
        #pragma unroll
        for (int i = 0; i < 4; ++i) {
            const int rg = row0 + wrow + i * 16 + quad * 4;
            const int b  = rg >> 9;
            const int j  = rg & 511;
            #pragma unroll
            for (int jt = 0; jt < 4; ++jt) {
                const int col = col0 + wcol + jt * 16 + lid;
                *(ushort4*)(Vt + (size_t)b * DD * MM + (size_t)col * MM + j) =
                    make_ushort4(rne_bf16(acc[i][jt][0]), rne_bf16(acc[i][jt][1]),
                                 rne_bf16(acc[i][jt][2]), rne_bf16(acc[i][jt][3]));
            }
        }
    } else {
        unsigned short* dst = (z == 0) ? Qa : Kb;
        const bool aform = (z == 0);
        #pragma unroll
        for (int i = 0; i < 4; ++i) {
            const int rg = row0 + wrow + i * 16 + quad * 4;
            #pragma unroll
            for (int r = 0; r < 4; ++r) {
                unsigned short* rowp = dst + (size_t)(rg + r) * K3;
                #pragma unroll
                for (int jt = 0; jt < 4; ++jt) {
                    const int col = col0 + wcol + jt * 16 + lid;
                    const float v = acc[i][jt][r];
                    unsigned short h = rne_bf16(v);
                    unsigned short l = rne_bf16(v - bf2f(h));
                    rowp[3*col+0] = h;
                    rowp[3*col+1] = aform ? l : h;
                    rowp[3*col+2] = aform ? h : l;
                }
            }
        }
    }
}

// ---------------------------------------------------------------------------
// Scores via MFMA (triple-split, K'=768), mask epilogue.
// mode 0: x-self; 1: y-self; 2: xy (bq=s*8+n, bk=s, writes mask floats).
// grid = (4, 4, nbatch)
// ---------------------------------------------------------------------------
__global__ __launch_bounds__(256) void scores_kernel(
    const unsigned short* __restrict__ Qa_base,
    const unsigned short* __restrict__ Kb_base,
    const int* __restrict__ mq_base, const int* __restrict__ mk_base,
    float* __restrict__ Sbase, float* __restrict__ Mbase, int mode)
{
    const int z = blockIdx.z;
    int bq, bk;
    if (mode == 2) { const int n = z >> 3, s = z & 7; bq = s * 8 + n; bk = s; }
    else           { bq = z; bk = z; }

    const int row0 = blockIdx.x * 128;
    const int col0 = blockIdx.y * 128;
    const unsigned short* Asrc = Qa_base + (size_t)(bq * MM + row0) * K3;
    const unsigned short* Bsrc = Kb_base + (size_t)(bk * MM + col0) * K3;
    const int* mq = mq_base + bq * MM;
    const int* mk = mk_base + bk * MM;
    float* S  = Sbase + (size_t)z * MM * MM;
    float* Mo = (mode == 2) ? (Mbase + (size_t)z * MM * MM) : nullptr;

    __shared__ unsigned short Ab[128][104];
    __shared__ unsigned short Bb[128][104];

    const int t = threadIdx.x;
    const int wave = t >> 6, lane = t & 63, quad = lane >> 4, lid = lane & 15;
    const int wrow = (wave & 1) * 64, wcol = (wave >> 1) * 64;

    f32x4 acc[4][4];
    #pragma unroll
    for (int i = 0; i < 4; ++i)
        #pragma unroll
        for (int j = 0; j < 4; ++j) acc[i][j] = (f32x4){0.f, 0.f, 0.f, 0.f};

    for (int ck = 0; ck < 8; ++ck) {
        stage_768(Ab, Asrc, ck, t);
        stage_768(Bb, Bsrc, ck, t);
        __syncthreads();
        #pragma unroll
        for (int kk = 0; kk < 96; kk += 32)
            mfma_tiles<104>(Ab, Bb, kk, wrow, wcol, lid, quad, acc);
        __syncthreads();
    }

    int mcol[4];
    #pragma unroll
    for (int jt = 0; jt < 4; ++jt) mcol[jt] = mk[col0 + wcol + jt * 16 + lid];

    #pragma unroll
    for (int i = 0; i < 4; ++i) {
        const int rg = row0 + wrow + i * 16 + quad * 4;
        #pragma unroll
        for (int r = 0; r < 4; ++r) {
            const bool mr = (mq[rg + r] != 0);
            float* Srow = S + (size_t)(rg + r) * MM;
            float* Mrow = Mo ? (Mo + (size_t)(rg + r) * MM) : nullptr;
            #pragma unroll
            for (int jt = 0; jt < 4; ++jt) {
                const int col = col0 + wcol + jt * 16 + lid;
                const bool valid = mr && (mcol[jt] != 0);
                Srow[col] = valid ? acc[i][jt][r] : NEG_FILL_F;
                if (Mrow) Mrow[col] = valid ? 1.0f : 0.0f;
            }
        }
    }
}

// ---------------------------------------------------------------------------
// Row stats: per row of 512, (max, 1/sum(exp(v-max))). One wave per row.
// ---------------------------------------------------------------------------
__global__ __launch_bounds__(256) void stats_kernel(
    const float* __restrict__ S, float2* __restrict__ st)
{
    const int wid  = threadIdx.x >> 6;
    const int lane = threadIdx.x & 63;
    const int row  = blockIdx.x * 4 + wid;
    const float* r = S + (size_t)row * MM;

    float4 v0 = *(const float4*)(r + lane * 8);
    float4 v1 = *(const float4*)(r + lane * 8 + 4);

    float m = fmaxf(fmaxf(fmaxf(v0.x, v0.y), fmaxf(v0.z, v0.w)),
                    fmaxf(fmaxf(v1.x, v1.y), fmaxf(v1.z, v1.w)));
    #pragma unroll
    for (int off = 32; off; off >>= 1) m = fmaxf(m, __shfl_xor(m, off));

    float s = __expf(v0.x - m) + __expf(v0.y - m) + __expf(v0.z - m) + __expf(v0.w - m)
            + __expf(v1.x - m) + __expf(v1.y - m) + __expf(v1.z - m) + __expf(v1.w - m);
    #pragma unroll
    for (int off = 32; off; off >>= 1) s += __shfl_xor(s, off);

    if (lane == 0) st[row] = make_float2(m, 1.0f / s);
}

// ---------------------------------------------------------------------------
// Context via MFMA (plain bf16, K'=512): O[i,d] = inv_i * sum_j e^{S-m} Vt[d,j]
// A staged with exp fused; B = Vt bf16. grid = (4, 2, nbatch)
// ---------------------------------------------------------------------------
__global__ __launch_bounds__(256) void ctx_kernel(
    const float* __restrict__ Sbase, const float2* __restrict__ stats,
    const unsigned short* __restrict__ Vt_base, float* __restrict__ Obase)
{
    const int b = blockIdx.z;
    const float*          S  = Sbase + (size_t)b * MM * MM;
    const float2*         st = stats + (size_t)b * MM;
    const unsigned short* Vt = Vt_base + (size_t)b * DD * MM;
    float*                O  = Obase + (size_t)b * MM * DD;

    const int row0 = blockIdx.x * 128;
    const int col0 = blockIdx.y * 128;

    __shared__ unsigned short Ab[128][72];
    __shared__ unsigned short Bb[128][72];

    const int t = threadIdx.x;
    const int wave = t >> 6, lane = t & 63, quad = lane >> 4, lid = lane & 15;
    const int wrow = (wave & 1) * 64, wcol = (wave >> 1) * 64;

    f32x4 acc[4][4];
    #pragma unroll
    for (int i = 0; i < 4; ++i)
        #pragma unroll
        for (int j = 0; j < 4; ++j) acc[i][j] = (f32x4){0.f, 0.f, 0.f, 0.f};

    for (int ck = 0; ck < 8; ++ck) {
        #pragma unroll
        for (int s = 0; s < 4; ++s) {
            const int c   = s * 256 + t;      // 0..1023
            const int row = c >> 3;
            const int j8  = (c & 7) * 8;
            const float* sp = S + (size_t)(row0 + row) * MM + ck * 64 + j8;
            float4 v0 = *(const float4*)sp;
            float4 v1 = *(const float4*)(sp + 4);
            const float pm = st[row0 + row].x;
            short8 pk;
            pk[0] = (short)rne_bf16(__expf(v0.x - pm));
            pk[1] = (short)rne_bf16(__expf(v0.y - pm));
            pk[2] = (short)rne_bf16(__expf(v0.z - pm));
            pk[3] = (short)rne_bf16(__expf(v0.w - pm));
            pk[4] = (short)rne_bf16(__expf(v1.x - pm));
            pk[5] = (short)rne_bf16(__expf(v1.y - pm));
            pk[6] = (short)rne_bf16(__expf(v1.z - pm));
            pk[7] = (short)rne_bf16(__expf(v1.w - pm));
            *(short8*)&Ab[row][j8] = pk;
            // B tile: Vt rows are d (cols of output)
            *(short8*)&Bb[row][j8] =
                *(const short8*)(Vt + (size_t)(col0 + row) * MM + ck * 64 + j8);
        }
        __syncthreads();
        #pragma unroll
        for (int kk = 0; kk < 64; kk += 32)
            mfma_tiles<72>(Ab, Bb, kk, wrow, wcol, lid, quad, acc);
        __syncthreads();
    }

    #pragma unroll
    for (int i = 0; i < 4; ++i) {
        const int rgb = row0 + wrow + i * 16 + quad * 4;
        float inv[4];
        #pragma unroll
        for (int r = 0; r < 4; ++r) inv[r] = st[rgb + r].y;
        #pragma unroll
        for (int jt = 0; jt < 4; ++jt) {
            const int col = col0 + wcol + jt * 16 + lid;
            #pragma unroll
            for (int r = 0; r < 4; ++r)
                O[(size_t)(rgb + r) * DD + col] = acc[i][jt][r] * inv[r];
        }
    }
}

// ---------------------------------------------------------------------------
// In-place softmax transform of the scores_xy slot -> probs_xy.
// ---------------------------------------------------------------------------
__global__ __launch_bounds__(128) void softmax_apply(
    float* __restrict__ S, const float2* __restrict__ stats)
{
    const int row = blockIdx.x;
    const float2 st = stats[row];
    float4* r = (float4*)(S + (size_t)row * MM) + threadIdx.x;
    float4 v = *r;
    v.x = __expf(v.x - st.x) * st.y;
    v.y = __expf(v.y - st.x) * st.y;
    v.z = __expf(v.z - st.x) * st.y;
    v.w = __expf(v.w - st.x) * st.y;
    *r = v;
}

// ---------------------------------------------------------------------------
// y_len[n, s] = sum_i mask_y[s, i]
// ---------------------------------------------------------------------------
__global__ void ylen_kernel(const int* __restrict__ mask_y, float* __restrict__ out)
{
    const int t = threadIdx.x;
    const int s = t & 7;
    int c = 0;
    for (int i = 0; i < MM; ++i) c += (mask_y[s * MM + i] != 0);
    out[t] = (float)c;
}

// ---------------------------------------------------------------------------
extern "C" void kernel_launch(void* const* d_in, const int* in_sizes, int n_in,
                              void* d_out, int out_size, void* d_ws, size_t ws_size,
                              hipStream_t stream)
{
    const float* x      = (const float*)d_in[0];
    const float* y      = (const float*)d_in[1];
    const int*   mask_x = (const int*)d_in[2];
    const int*   mask_y = (const int*)d_in[3];
    const float* Wq     = (const float*)d_in[4];
    const float* Wk     = (const float*)d_in[5];
    const float* Wv     = (const float*)d_in[6];
    float* out = (float*)d_out;

    // Workspace (~134 MB): Wb | Qa | Kb | Vt | stats
    unsigned short* Wb = (unsigned short*)d_ws;            // 3*256*768      = 589824
    unsigned short* Qa = Wb + 589824;                      // 36864*768      = 28311552
    unsigned short* Kb = Qa + 28311552;
    unsigned short* Vt = Kb + 28311552;                    // 72*256*512     = 9437184
    float2* stats_x  = (float2*)(Vt + 9437184);
    float2* stats_y  = stats_x + ROWS_X;
    float2* stats_xy = stats_y + ROWS_Y;

    // Output slots (floats, concatenated in reference return order)
    float* out_ctx_x = out;                 // 64*512*256   = 8388608
    float* out_ctx_y = out + 8388608;       // 8*512*256    = 1048576
    float* out_sx    = out + 9437184;       // 64*512*512   = 16777216
    float* out_sy    = out + 26214400;      // 8*512*512    = 2097152
    float* out_pxy   = out + 28311552;      // 8*8*512*512  = 16777216
    float* out_mxy   = out + 45088768;      // 8*8*512*512  = 16777216
    float* out_ylen  = out + 61865984;      // 8*8          = 64

    // 1. W -> split form
    convw_kernel<<<96, 256, 0, stream>>>(Wq, Wk, Wv, Wb);

    // 2. Projections (MFMA), writing split Qa/Kb and transposed bf16 Vt
    proj_kernel<<<dim3(288, 2, 3), 256, 0, stream>>>(x, y, Wb, Qa, Kb, Vt);

    const unsigned short* Qa_y = Qa + (size_t)ROWS_X * K3;
    const unsigned short* Kb_y = Kb + (size_t)ROWS_X * K3;

    // 3. Masked scores straight into output slots (MFMA)
    scores_kernel<<<dim3(4, 4, 64), 256, 0, stream>>>(Qa,   Kb,   mask_x, mask_x, out_sx,  nullptr, 0);
    scores_kernel<<<dim3(4, 4, 8),  256, 0, stream>>>(Qa_y, Kb_y, mask_y, mask_y, out_sy,  nullptr, 1);
    scores_kernel<<<dim3(4, 4, 64), 256, 0, stream>>>(Qa,   Kb_y, mask_x, mask_y, out_pxy, out_mxy, 2);

    // 4. Softmax row stats
    stats_kernel<<<ROWS_X / 4, 256, 0, stream>>>(out_sx,  stats_x);
    stats_kernel<<<ROWS_Y / 4, 256, 0, stream>>>(out_sy,  stats_y);
    stats_kernel<<<ROWS_X / 4, 256, 0, stream>>>(out_pxy, stats_xy);

    // 5. Context GEMMs (MFMA, exp fused on A-stage)
    ctx_kernel<<<dim3(4, 2, 64), 256, 0, stream>>>(out_sx, stats_x, Vt, out_ctx_x);
    ctx_kernel<<<dim3(4, 2, 8),  256, 0, stream>>>(out_sy, stats_y,
                                                   Vt + (size_t)64 * DD * MM, out_ctx_y);

    // 6. scores_xy -> probs_xy in place
    softmax_apply<<<ROWS_X, 128, 0, stream>>>(out_pxy, stats_xy);

    // 7. y_len
    ylen_kernel<<<1, 64, 0, stream>>>(mask_y, out_ylen);
}

// Round 6
// 550.354 us; speedup vs baseline: 1.9898x; 1.0333x over previous
//
#include <hip/hip_runtime.h>
#include <cstdint>

// Problem constants (B, BS, M, D) = (64, 8, 512, 256), neg = B/BS = 8
#define NEG_FILL_F (-10000000000.0f)
constexpr int BB     = 64;
constexpr int BS_    = 8;
constexpr int MM     = 512;
constexpr int DD     = 256;
constexpr int ROWS_X = BB * MM;           // 32768
constexpr int ROWS_Y = BS_ * MM;          // 4096
constexpr int ROWS_ALL = ROWS_X + ROWS_Y; // 36864
constexpr int K3     = 768;               // triple-split K' = 3*DD

typedef __attribute__((ext_vector_type(8))) short short8;   // 8 bf16 = 4 VGPRs
typedef __attribute__((ext_vector_type(4))) float f32x4;    // MFMA C/D

__device__ inline unsigned short rne_bf16(float f) {
    unsigned int u = __float_as_uint(f);
    u = (u + 0x7FFFu + ((u >> 16) & 1u)) >> 16;
    return (unsigned short)u;
}
__device__ inline float bf2f(unsigned short h) {
    return __uint_as_float(((unsigned int)h) << 16);
}

__device__ inline f32x4 mfma16(short8 a, short8 b, f32x4 c) {
    return __builtin_amdgcn_mfma_f32_16x16x32_bf16(a, b, c, 0, 0, 0);
}

// Async global->LDS 16B copy (direct-to-shared DMA). LDS dst is wave-uniform
// base; HW adds lane*16. Requires contiguous lane-ordered LDS layout (no pad).
__device__ inline void gld16(const unsigned short* g, unsigned short* l) {
    __builtin_amdgcn_global_load_lds(
        (const __attribute__((address_space(1))) unsigned int*)g,
        (__attribute__((address_space(3))) unsigned int*)l, 16, 0, 0);
}

// Fragment loads + 16 MFMAs for one kk step. LDS layout: T[row][k] row-major.
// A: lane holds A[m=lid][k=quad*8+j]; B: B[k=quad*8+j][n=lid].
template<int LDA, int LDB>
__device__ inline void mfma_tiles(const unsigned short (*Ab)[LDA],
                                  const unsigned short (*Bb)[LDB],
                                  int kk, int wrow, int wcol, int lid, int quad,
                                  f32x4 acc[4][4])
{
    short8 af[4], bfr[4];
    #pragma unroll
    for (int i = 0; i < 4; ++i)
        af[i] = *(const short8*)&Ab[wrow + i * 16 + lid][kk + quad * 8];
    #pragma unroll
    for (int j = 0; j < 4; ++j)
        bfr[j] = *(const short8*)&Bb[wcol + j * 16 + lid][kk + quad * 8];
    #pragma unroll
    for (int i = 0; i < 4; ++i)
        #pragma unroll
        for (int j = 0; j < 4; ++j)
            acc[i][j] = mfma16(af[i], bfr[j], acc[i][j]);
}

// Async-stage a 128-row x 96-bf16 tile from a stride-768 bf16 array into
// unpadded LDS [128][96]. Chunk c (16B) -> LDS byte c*16 (lane-contiguous).
__device__ inline void stage768_async(unsigned short* dstbase,
                                      const unsigned short* __restrict__ src,
                                      int ck, int wave, int lane)
{
    #pragma unroll
    for (int s = 0; s < 6; ++s) {
        const int c   = s * 256 + wave * 64 + lane;  // 0..1535
        const int row = c / 12;
        const int kc  = (c % 12) * 8;
        gld16(src + (size_t)row * K3 + ck * 96 + kc,
              dstbase + (size_t)(s * 256 + wave * 64) * 8);
    }
}

// Manual stage: 128-row x 32-f32 -> 96 bf16 triple-split A-form (h,l,h).
__device__ inline void stage_x96(unsigned short (*dst)[96],
                                 const float* __restrict__ src,
                                 int ck, int t)
{
    #pragma unroll
    for (int s = 0; s < 4; ++s) {
        const int c   = s * 256 + t;        // 0..1023
        const int row = c >> 3;             // 0..127
        const int q4  = (c & 7) * 4;        // 0,4,...,28
        float4 v = *(const float4*)(src + (size_t)row * DD + ck * 32 + q4);
        const float fv[4] = {v.x, v.y, v.z, v.w};
        unsigned short o[12];
        #pragma unroll
        for (int e = 0; e < 4; ++e) {
            unsigned short h = rne_bf16(fv[e]);
            unsigned short l = rne_bf16(fv[e] - bf2f(h));
            o[e*3+0] = h; o[e*3+1] = l; o[e*3+2] = h;
        }
        ushort4* p = (ushort4*)&dst[row][q4 * 3];
        p[0] = make_ushort4(o[0], o[1], o[2],  o[3]);
        p[1] = make_ushort4(o[4], o[5], o[6],  o[7]);
        p[2] = make_ushort4(o[8], o[9], o[10], o[11]);
    }
}

// ---------------------------------------------------------------------------
// W -> Wb: [3][256][768] triple-split B-form (h,h,l). 96 blocks x 256.
// ---------------------------------------------------------------------------
__global__ __launch_bounds__(256) void convw_kernel(
    const float* __restrict__ Wq, const float* __restrict__ Wk,
    const float* __restrict__ Wv, unsigned short* __restrict__ Wb)
{
    const int g  = blockIdx.x * 256 + threadIdx.x;   // < 24576
    const int e  = g * 8;                            // over 3*65536
    const int zi = e >> 16;
    const int off = e & 65535;
    const float* W = (zi == 0) ? Wq : (zi == 1 ? Wk : Wv);
    float4 v0 = *(const float4*)(W + off);
    float4 v1 = *(const float4*)(W + off + 4);
    const float fv[8] = {v0.x, v0.y, v0.z, v0.w, v1.x, v1.y, v1.z, v1.w};
    unsigned short o[24];
    #pragma unroll
    for (int i = 0; i < 8; ++i) {
        unsigned short h = rne_bf16(fv[i]);
        unsigned short l = rne_bf16(fv[i] - bf2f(h));
        o[i*3+0] = h; o[i*3+1] = h; o[i*3+2] = l;
    }
    unsigned short* dst = Wb + (size_t)zi * 196608 + (size_t)off * 3;
    #pragma unroll
    for (int s = 0; s < 3; ++s) {
        short8 v;
        #pragma unroll
        for (int e2 = 0; e2 < 8; ++e2) v[e2] = (short)o[s*8+e2];
        *(short8*)(dst + s * 8) = v;
    }
}

// ---------------------------------------------------------------------------
// Projections via MFMA (K'=768). A manual-split staged; B async-copied.
// z=0 -> Qa (A-form), z=1 -> Kb (B-form), z=2 -> Vt[b][d][j] plain bf16.
// grid = (288, 2, 3)
// ---------------------------------------------------------------------------
__global__ __launch_bounds__(256) void proj_kernel(
    const float* __restrict__ x, const float* __restrict__ y,
    const unsigned short* __restrict__ Wb,
    unsigned short* __restrict__ Qa, unsigned short* __restrict__ Kb,
    unsigned short* __restrict__ Vt)
{
    const int z    = blockIdx.z;
    const int row0 = blockIdx.x * 128;
    const int col0 = blockIdx.y * 128;
    const float* A = (row0 < ROWS_X) ? (x + (size_t)row0 * DD)
                                     : (y + (size_t)(row0 - ROWS_X) * DD);
    const unsigned short* Bsrc = Wb + (size_t)z * 196608 + (size_t)col0 * K3;

    __shared__ unsigned short Ab[128][96];
    __shared__ unsigned short Bb[128][96];

    const int t = threadIdx.x;
    const int wave = t >> 6, lane = t & 63, quad = lane >> 4, lid = lane & 15;
    const int wrow = (wave & 1) * 64, wcol = (wave >> 1) * 64;

    f32x4 acc[4][4];
    #pragma unroll
    for (int i = 0; i < 4; ++i)
        #pragma unroll
        for (int j = 0; j < 4; ++j) acc[i][j] = (f32x4){0.f, 0.f, 0.f, 0.f};

    for (int ck = 0; ck < 8; ++ck) {
        stage768_async(&Bb[0][0], Bsrc, ck, wave, lane);
        stage_x96(Ab, A, ck, t);
        __syncthreads();
        #pragma unroll
        for (int kk = 0; kk < 96; kk += 32)
            mfma_tiles<96,96>(Ab, Bb, kk, wrow, wcol, lid, quad, acc);
        __syncthreads();
    }

    if (z == 2) {
        #pragma unroll
        for (int i = 0; i < 4; ++i) {
            const int rg = row0 + wrow + i * 16 + quad * 4;
            const int b  = rg >> 9;
            const int j  = rg & 511;
            #pragma unroll
            for (int jt = 0; jt < 4; ++jt) {
                const int col = col0 + wcol + jt * 16 + lid;
                *(ushort4*)(Vt + (size_t)b * DD * MM + (size_t)col * MM + j) =
                    make_ushort4(rne_bf16(acc[i][jt][0]), rne_bf16(acc[i][jt][1]),
                                 rne_bf16(acc[i][jt][2]), rne_bf16(acc[i][jt][3]));
            }
        }
    } else {
        unsigned short* dst = (z == 0) ? Qa : Kb;
        const bool aform = (z == 0);
        #pragma unroll
        for (int i = 0; i < 4; ++i) {
            const int rg = row0 + wrow + i * 16 + quad * 4;
            #pragma unroll
            for (int r = 0; r < 4; ++r) {
                unsigned short* rowp = dst + (size_t)(rg + r) * K3;
                #pragma unroll
                for (int jt = 0; jt < 4; ++jt) {
                    const int col = col0 + wcol + jt * 16 + lid;
                    const float v = acc[i][jt][r];
                    unsigned short h = rne_bf16(v);
                    unsigned short l = rne_bf16(v - bf2f(h));
                    rowp[3*col+0] = h;
                    rowp[3*col+1] = aform ? l : h;
                    rowp[3*col+2] = aform ? h : l;
                }
            }
        }
    }
}

// ---------------------------------------------------------------------------
// Scores via MFMA (K'=768), async staging, mask epilogue + fused per-block
// softmax partials (max, sumexp) -> pstats[z][4 colblk][512].
// mode 0: x-self; 1: y-self; 2: xy (bq=s*8+n, bk=s, writes mask floats).
// grid = (4, 4, nbatch)
// ---------------------------------------------------------------------------
__global__ __launch_bounds__(256) void scores_kernel(
    const unsigned short* __restrict__ Qa_base,
    const unsigned short* __restrict__ Kb_base,
    const int* __restrict__ mq_base, const int* __restrict__ mk_base,
    float* __restrict__ Sbase, float* __restrict__ Mbase,
    float2* __restrict__ pstats, int mode)
{
    const int z = blockIdx.z;
    int bq, bk;
    if (mode == 2) { const int n = z >> 3, s = z & 7; bq = s * 8 + n; bk = s; }
    else           { bq = z; bk = z; }

    const int row0 = blockIdx.x * 128;
    const int col0 = blockIdx.y * 128;
    const unsigned short* Asrc = Qa_base + (size_t)(bq * MM + row0) * K3;
    const unsigned short* Bsrc = Kb_base + (size_t)(bk * MM + col0) * K3;
    const int* mq = mq_base + bq * MM;
    const int* mk = mk_base + bk * MM;
    float* S  = Sbase + (size_t)z * MM * MM;
    float* Mo = (mode == 2) ? (Mbase + (size_t)z * MM * MM) : nullptr;

    __shared__ unsigned short Ab[128][96];
    __shared__ unsigned short Bb[128][96];
    __shared__ float pm2[128][2];
    __shared__ float ps2[128][2];

    const int t = threadIdx.x;
    const int wave = t >> 6, lane = t & 63, quad = lane >> 4, lid = lane & 15;
    const int wrow = (wave & 1) * 64, wcol = (wave >> 1) * 64;

    f32x4 acc[4][4];
    #pragma unroll
    for (int i = 0; i < 4; ++i)
        #pragma unroll
        for (int j = 0; j < 4; ++j) acc[i][j] = (f32x4){0.f, 0.f, 0.f, 0.f};

    for (int ck = 0; ck < 8; ++ck) {
        stage768_async(&Ab[0][0], Asrc, ck, wave, lane);
        stage768_async(&Bb[0][0], Bsrc, ck, wave, lane);
        __syncthreads();
        #pragma unroll
        for (int kk = 0; kk < 96; kk += 32)
            mfma_tiles<96,96>(Ab, Bb, kk, wrow, wcol, lid, quad, acc);
        __syncthreads();
    }

    int mcol[4];
    #pragma unroll
    for (int jt = 0; jt < 4; ++jt) mcol[jt] = mk[col0 + wcol + jt * 16 + lid];

    #pragma unroll
    for (int i = 0; i < 4; ++i) {
        const int rl0 = wrow + i * 16 + quad * 4;        // local row base
        #pragma unroll
        for (int r = 0; r < 4; ++r) {
            const int rlocal = rl0 + r;
            const int rg = row0 + rlocal;
            const bool mr = (mq[rg] != 0);
            float* Srow = S + (size_t)rg * MM;
            float* Mrow = Mo ? (Mo + (size_t)rg * MM) : nullptr;
            float v[4];
            float mt = -3.4e38f;
            #pragma unroll
            for (int jt = 0; jt < 4; ++jt) {
                const int col = col0 + wcol + jt * 16 + lid;
                const bool valid = mr && (mcol[jt] != 0);
                v[jt] = valid ? acc[i][jt][r] : NEG_FILL_F;
                Srow[col] = v[jt];
                if (Mrow) Mrow[col] = valid ? 1.0f : 0.0f;
                mt = fmaxf(mt, v[jt]);
            }
            #pragma unroll
            for (int o = 1; o < 16; o <<= 1) mt = fmaxf(mt, __shfl_xor(mt, o));
            float se = 0.f;
            #pragma unroll
            for (int jt = 0; jt < 4; ++jt) se += __expf(v[jt] - mt);
            #pragma unroll
            for (int o = 1; o < 16; o <<= 1) se += __shfl_xor(se, o);
            if (lid == 0) { pm2[rlocal][wave >> 1] = mt; ps2[rlocal][wave >> 1] = se; }
        }
    }
    __syncthreads();
    if (t < 128) {
        const float m0 = pm2[t][0], m1 = pm2[t][1];
        const float mm = fmaxf(m0, m1);
        const float ss = ps2[t][0] * __expf(m0 - mm) + ps2[t][1] * __expf(m1 - mm);
        pstats[(size_t)(z * 4 + blockIdx.y) * MM + row0 + t] = make_float2(mm, ss);
    }
}

// ---------------------------------------------------------------------------
// Merge 4 col-block partials per row -> (max, 1/sum). grid = nrows/256.
// All-masked rows merge to (NEG_FILL, 1/512) = uniform softmax (jax match).
// ---------------------------------------------------------------------------
__global__ __launch_bounds__(256) void reduce4_kernel(
    const float2* __restrict__ p, float2* __restrict__ st)
{
    const int row = blockIdx.x * 256 + threadIdx.x;
    const int z = row >> 9, rl = row & 511;
    float m = -3.4e38f, s = 0.f;
    #pragma unroll
    for (int by = 0; by < 4; ++by) {
        float2 v = p[(size_t)(z * 4 + by) * MM + rl];
        float nm = fmaxf(m, v.x);
        s = s * __expf(m - nm) + v.y * __expf(v.x - nm);
        m = nm;
    }
    st[row] = make_float2(m, 1.0f / s);
}

// ---------------------------------------------------------------------------
// Context via MFMA (plain bf16, K'=512). A = exp(S-m) manual-staged (pad 72);
// B = Vt async-copied (unpadded 64). grid = (4, 2, nbatch)
// ---------------------------------------------------------------------------
__global__ __launch_bounds__(256) void ctx_kernel(
    const float* __restrict__ Sbase, const float2* __restrict__ stats,
    const unsigned short* __restrict__ Vt_base, float* __restrict__ Obase)
{
    const int b = blockIdx.z;
    const float*          S  = Sbase + (size_t)b * MM * MM;
    const float2*         st = stats + (size_t)b * MM;
    const unsigned short* Vt = Vt_base + (size_t)b * DD * MM;
    float*                O  = Obase + (size_t)b * MM * DD;

    const int row0 = blockIdx.x * 128;
    const int col0 = blockIdx.y * 128;

    __shared__ unsigned short Ab[128][72];
    __shared__ unsigned short Bb[128][64];

    const int t = threadIdx.x;
    const int wave = t >> 6, lane = t & 63, quad = lane >> 4, lid = lane & 15;
    const int wrow = (wave & 1) * 64, wcol = (wave >> 1) * 64;

    f32x4 acc[4][4];
    #pragma unroll
    for (int i = 0; i < 4; ++i)
        #pragma unroll
        for (int j = 0; j < 4; ++j) acc[i][j] = (f32x4){0.f, 0.f, 0.f, 0.f};

    for (int ck = 0; ck < 8; ++ck) {
        // B: Vt rows are d (output cols); 1024 16B-chunks, lane-contiguous
        #pragma unroll
        for (int s = 0; s < 4; ++s) {
            const int c   = s * 256 + wave * 64 + lane;  // 0..1023
            const int row = c >> 3;
            const int j8  = (c & 7) * 8;
            gld16(Vt + (size_t)(col0 + row) * MM + ck * 64 + j8,
                  &Bb[0][0] + (size_t)(s * 256 + wave * 64) * 8);
        }
        // A: exp(S - m) -> bf16, manual
        #pragma unroll
        for (int s = 0; s < 4; ++s) {
            const int c   = s * 256 + t;      // 0..1023
            const int row = c >> 3;
            const int j8  = (c & 7) * 8;
            const float* sp = S + (size_t)(row0 + row) * MM + ck * 64 + j8;
            float4 v0 = *(const float4*)sp;
            float4 v1 = *(const float4*)(sp + 4);
            const float pm = st[row0 + row].x;
            short8 pk;
            pk[0] = (short)rne_bf16(__expf(v0.x - pm));
            pk[1] = (short)rne_bf16(__expf(v0.y - pm));
            pk[2] = (short)rne_bf16(__expf(v0.z - pm));
            pk[3] = (short)rne_bf16(__expf(v0.w - pm));
            pk[4] = (short)rne_bf16(__expf(v1.x - pm));
            pk[5] = (short)rne_bf16(__expf(v1.y - pm));
            pk[6] = (short)rne_bf16(__expf(v1.z - pm));
            pk[7] = (short)rne_bf16(__expf(v1.w - pm));
            *(short8*)&Ab[row][j8] = pk;
        }
        __syncthreads();
        #pragma unroll
        for (int kk = 0; kk < 64; kk += 32)
            mfma_tiles<72,64>(Ab, Bb, kk, wrow, wcol, lid, quad, acc);
        __syncthreads();
    }

    #pragma unroll
    for (int i = 0; i < 4; ++i) {
        const int rgb = row0 + wrow + i * 16 + quad * 4;
        float inv[4];
        #pragma unroll
        for (int r = 0; r < 4; ++r) inv[r] = st[rgb + r].y;
        #pragma unroll
        for (int jt = 0; jt < 4; ++jt) {
            const int col = col0 + wcol + jt * 16 + lid;
            #pragma unroll
            for (int r = 0; r < 4; ++r)
                O[(size_t)(rgb + r) * DD + col] = acc[i][jt][r] * inv[r];
        }
    }
}

// ---------------------------------------------------------------------------
// In-place softmax transform of the scores_xy slot -> probs_xy.
// ---------------------------------------------------------------------------
__global__ __launch_bounds__(128) void softmax_apply(
    float* __restrict__ S, const float2* __restrict__ stats)
{
    const int row = blockIdx.x;
    const float2 st = stats[row];
    float4* r = (float4*)(S + (size_t)row * MM) + threadIdx.x;
    float4 v = *r;
    v.x = __expf(v.x - st.x) * st.y;
    v.y = __expf(v.y - st.x) * st.y;
    v.z = __expf(v.z - st.x) * st.y;
    v.w = __expf(v.w - st.x) * st.y;
    *r = v;
}

// ---------------------------------------------------------------------------
// y_len: one block per s, 64-lane reduce of mask_y[s,:]; lane n<8 writes n*8+s.
// ---------------------------------------------------------------------------
__global__ void ylen_kernel(const int* __restrict__ mask_y, float* __restrict__ out)
{
    const int s = blockIdx.x;
    const int lane = threadIdx.x;
    int c = 0;
    #pragma unroll
    for (int k = 0; k < 8; ++k) c += (mask_y[s * MM + k * 64 + lane] != 0);
    #pragma unroll
    for (int off = 32; off; off >>= 1) c += __shfl_xor(c, off);
    if (lane < 8) out[lane * 8 + s] = (float)c;
}

// ---------------------------------------------------------------------------
extern "C" void kernel_launch(void* const* d_in, const int* in_sizes, int n_in,
                              void* d_out, int out_size, void* d_ws, size_t ws_size,
                              hipStream_t stream)
{
    const float* x      = (const float*)d_in[0];
    const float* y      = (const float*)d_in[1];
    const int*   mask_x = (const int*)d_in[2];
    const int*   mask_y = (const int*)d_in[3];
    const float* Wq     = (const float*)d_in[4];
    const float* Wk     = (const float*)d_in[5];
    const float* Wv     = (const float*)d_in[6];
    float* out = (float*)d_out;

    // Workspace (~136 MB): Wb | Qa | Kb | Vt | stats | pstats
    unsigned short* Wb = (unsigned short*)d_ws;            // 3*256*768      = 589824
    unsigned short* Qa = Wb + 589824;                      // 36864*768      = 28311552
    unsigned short* Kb = Qa + 28311552;
    unsigned short* Vt = Kb + 28311552;                    // 72*256*512     = 9437184
    float2* stats_x  = (float2*)(Vt + 9437184);
    float2* stats_y  = stats_x + ROWS_X;
    float2* stats_xy = stats_y + ROWS_Y;
    float2* ps_x  = stats_xy + ROWS_X;                     // 64*4*512
    float2* ps_y  = ps_x + 64 * 4 * 512;                   // 8*4*512
    float2* ps_xy = ps_y + 8 * 4 * 512;                    // 64*4*512

    // Output slots (floats, concatenated in reference return order)
    float* out_ctx_x = out;                 // 64*512*256   = 8388608
    float* out_ctx_y = out + 8388608;       // 8*512*256    = 1048576
    float* out_sx    = out + 9437184;       // 64*512*512   = 16777216
    float* out_sy    = out + 26214400;      // 8*512*512    = 2097152
    float* out_pxy   = out + 28311552;      // 8*8*512*512  = 16777216
    float* out_mxy   = out + 45088768;      // 8*8*512*512  = 16777216
    float* out_ylen  = out + 61865984;      // 8*8          = 64

    // 1. W -> split form
    convw_kernel<<<96, 256, 0, stream>>>(Wq, Wk, Wv, Wb);

    // 2. Projections (MFMA), writing split Qa/Kb and transposed bf16 Vt
    proj_kernel<<<dim3(288, 2, 3), 256, 0, stream>>>(x, y, Wb, Qa, Kb, Vt);

    const unsigned short* Qa_y = Qa + (size_t)ROWS_X * K3;
    const unsigned short* Kb_y = Kb + (size_t)ROWS_X * K3;

    // 3. Masked scores + fused softmax partials
    scores_kernel<<<dim3(4, 4, 64), 256, 0, stream>>>(Qa,   Kb,   mask_x, mask_x, out_sx,  nullptr, ps_x,  0);
    scores_kernel<<<dim3(4, 4, 8),  256, 0, stream>>>(Qa_y, Kb_y, mask_y, mask_y, out_sy,  nullptr, ps_y,  1);
    scores_kernel<<<dim3(4, 4, 64), 256, 0, stream>>>(Qa,   Kb_y, mask_x, mask_y, out_pxy, out_mxy, ps_xy, 2);

    // 4. Merge partials -> (max, 1/sum)
    reduce4_kernel<<<ROWS_X / 256, 256, 0, stream>>>(ps_x,  stats_x);
    reduce4_kernel<<<ROWS_Y / 256, 256, 0, stream>>>(ps_y,  stats_y);
    reduce4_kernel<<<ROWS_X / 256, 256, 0, stream>>>(ps_xy, stats_xy);

    // 5. Context GEMMs (MFMA, exp fused on A-stage)
    ctx_kernel<<<dim3(4, 2, 64), 256, 0, stream>>>(out_sx, stats_x, Vt, out_ctx_x);
    ctx_kernel<<<dim3(4, 2, 8),  256, 0, stream>>>(out_sy, stats_y,
                                                   Vt + (size_t)64 * DD * MM, out_ctx_y);

    // 6. scores_xy -> probs_xy in place
    softmax_apply<<<ROWS_X, 128, 0, stream>>>(out_pxy, stats_xy);

    // 7. y_len
    ylen_kernel<<<8, 64, 0, stream>>>(mask_y, out_ylen);
}